// Round 3
// baseline (383.532 us; speedup 1.0000x reference)
//
#include <hip/hip_runtime.h>

typedef __bf16 bf16;
typedef __bf16 bf16x8 __attribute__((ext_vector_type(8)));
typedef float f32x4 __attribute__((ext_vector_type(4)));

__device__ __forceinline__ void gload_lds16(const void* g, void* l) {
  __builtin_amdgcn_global_load_lds(
      (const __attribute__((address_space(1))) void*)g,
      (__attribute__((address_space(3))) void*)l, 16, 0, 0);
}

__device__ __forceinline__ bf16x8 ld8(const bf16* p) {
  bf16x8 v; __builtin_memcpy(&v, p, 16); return v;
}

// ---------------- cast x (fp32 -> bf16), 8 elems/thread ----------------
__global__ __launch_bounds__(256) void cast_f32_bf16(const float* __restrict__ in,
                                                     bf16* __restrict__ out, int n8) {
  int i = blockIdx.x * 256 + threadIdx.x;
  if (i >= n8) return;
  const float4* p = (const float4*)in + (size_t)i * 2;
  float4 a = p[0], b = p[1];
  bf16x8 o;
  o[0] = (bf16)a.x; o[1] = (bf16)a.y; o[2] = (bf16)a.z; o[3] = (bf16)a.w;
  o[4] = (bf16)b.x; o[5] = (bf16)b.y; o[6] = (bf16)b.z; o[7] = (bf16)b.w;
  *((bf16x8*)out + i) = o;
}

// ---------------- transpose W (fp32 [K][N]) -> Wt (bf16 [N][K]) ----------------
__global__ __launch_bounds__(256) void transpose_w(const float* __restrict__ W,
                                                   bf16* __restrict__ Wt) {
  __shared__ bf16 tile[64][72];
  int t = threadIdx.x;
  int k0 = blockIdx.x * 64, n0 = blockIdx.y * 64;
  int r = t >> 2, c0 = (t & 3) * 16;
  const float* src = W + (size_t)(k0 + r) * 1536 + n0 + c0;
#pragma unroll
  for (int q = 0; q < 4; ++q) {
    float4 v = *(const float4*)(src + q * 4);
    tile[c0 + q * 4 + 0][r] = (bf16)v.x;
    tile[c0 + q * 4 + 1][r] = (bf16)v.y;
    tile[c0 + q * 4 + 2][r] = (bf16)v.z;
    tile[c0 + q * 4 + 3][r] = (bf16)v.w;
  }
  __syncthreads();
  bf16* dst = Wt + (size_t)(n0 + r) * 1536 + k0 + c0;
  bf16x8 o0, o1;
#pragma unroll
  for (int j = 0; j < 8; ++j) { o0[j] = tile[r][c0 + j]; o1[j] = tile[r][c0 + 8 + j]; }
  *(bf16x8*)dst = o0;
  *(bf16x8*)(dst + 8) = o1;
}

__global__ void concat_bias(const float* __restrict__ bq, const float* __restrict__ bk,
                            const float* __restrict__ bv, float* __restrict__ o) {
  int t = blockIdx.x * 256 + threadIdx.x;
  if (t < 1536) o[t] = bq[t];
  else if (t < 3072) o[t] = bk[t - 1536];
  else if (t < 4608) o[t] = bv[t - 3072];
}

// ---------------- m97-structure GEMM: C[M][N] = A[M][K](bf16) * B[N][K](bf16)^T + bias ----------------
template <typename OUT>
__global__ __launch_bounds__(256, 2) void gemm_bt(const bf16* __restrict__ A, const bf16* __restrict__ B,
                                                  const float* __restrict__ bias, OUT* __restrict__ C,
                                                  int M, int N, int K) {
  __shared__ bf16 As[128 * 32], Bs[128 * 32];
  int t = threadIdx.x, l = t & 63, w = t >> 6;
  int lane15 = l & 15, lhi = l >> 4;
  int m0 = blockIdx.x * 128, n0 = blockIdx.y * 128;
  int wm = (w >> 1) * 64, wn = (w & 1) * 64;
  f32x4 zero = {0.f, 0.f, 0.f, 0.f};
  f32x4 acc[4][4];
#pragma unroll
  for (int i = 0; i < 4; ++i)
#pragma unroll
    for (int j = 0; j < 4; ++j) acc[i][j] = zero;

  int srow = t >> 2, scol = (t & 3) * 8;
  const bf16* gA0 = A + (size_t)(m0 + srow) * K + scol;
  const bf16* gA1 = A + (size_t)(m0 + 64 + srow) * K + scol;
  const bf16* gB0 = B + (size_t)(n0 + srow) * K + scol;
  const bf16* gB1 = B + (size_t)(n0 + 64 + srow) * K + scol;
  char* ldsA = (char*)As + (size_t)w * 1024;
  char* ldsB = (char*)Bs + (size_t)w * 1024;

  for (int kt = 0; kt < K; kt += 32) {
    gload_lds16(gA0 + kt, ldsA);
    gload_lds16(gA1 + kt, ldsA + 4096);
    gload_lds16(gB0 + kt, ldsB);
    gload_lds16(gB1 + kt, ldsB + 4096);
    __syncthreads();
    bf16x8 af[4], bfr[4];
#pragma unroll
    for (int i = 0; i < 4; ++i) {
      af[i]  = ld8(&As[(wm + i * 16 + lane15) * 32 + lhi * 8]);
      bfr[i] = ld8(&Bs[(wn + i * 16 + lane15) * 32 + lhi * 8]);
    }
#pragma unroll
    for (int i = 0; i < 4; ++i)
#pragma unroll
      for (int j = 0; j < 4; ++j)
        acc[i][j] = __builtin_amdgcn_mfma_f32_16x16x32_bf16(af[i], bfr[j], acc[i][j], 0, 0, 0);
    __syncthreads();
  }
#pragma unroll
  for (int i = 0; i < 4; ++i)
#pragma unroll
    for (int j = 0; j < 4; ++j) {
      int col = n0 + wn + j * 16 + lane15;
      float bb = bias[col];
#pragma unroll
      for (int r = 0; r < 4; ++r) {
        int row = m0 + wm + i * 16 + lhi * 4 + r;
        C[(size_t)row * N + col] = (OUT)(acc[i][j][r] + bb);
      }
    }
}

// ---------------- RoPE cos/sin table [3584][64] ----------------
__global__ void rope_tab(const float* __restrict__ freqs, const int* __restrict__ gs,
                         float* __restrict__ tabc, float* __restrict__ tabs) {
  int idx = blockIdx.x * 256 + threadIdx.x;
  if (idx >= 3584 * 64) return;
  int s = idx >> 6, i = idx & 63;
  int H = gs[1], W = gs[2];   // int32 on device (harness converts integer inputs)
  int f = s / (H * W);
  int rem = s - f * (H * W);
  int hh = rem / W;
  int ww = rem - hh * W;
  int row = (i < 22) ? f : ((i < 43) ? hh : ww);
  float a = freqs[row * 64 + i];
  tabc[idx] = cosf(a);
  tabs[idx] = sinf(a);
}

// ---------------- RMSNorm + RoPE for Q,K; write head-major bf16 ----------------
__global__ __launch_bounds__(256) void postproc(const bf16* __restrict__ QKV,
    const float* __restrict__ gq, const float* __restrict__ gk,
    const float* __restrict__ tabc, const float* __restrict__ tabs,
    bf16* __restrict__ qb, bf16* __restrict__ kb) {
  int s = blockIdx.x, t = threadIdx.x;
  const bf16* Qr = QKV + (size_t)s * 4608;
  const bf16* Kr = Qr + 1536;
  int j0 = t * 6;
  float qv[6], kv[6];
  float sq = 0.f, sk = 0.f;
#pragma unroll
  for (int j = 0; j < 6; ++j) {
    float a = (float)Qr[j0 + j]; qv[j] = a; sq += a * a;
    float b = (float)Kr[j0 + j]; kv[j] = b; sk += b * b;
  }
#pragma unroll
  for (int off = 32; off > 0; off >>= 1) {
    sq += __shfl_down(sq, off);
    sk += __shfl_down(sk, off);
  }
  __shared__ float red[2][4];
  if ((t & 63) == 0) { red[0][t >> 6] = sq; red[1][t >> 6] = sk; }
  __syncthreads();
  float vq = (red[0][0] + red[0][1]) + (red[0][2] + red[0][3]);
  float vk = (red[1][0] + red[1][1]) + (red[1][2] + red[1][3]);
  float rq = 1.0f / sqrtf(vq * (1.0f / 1536.0f) + 1e-6f);
  float rk = 1.0f / sqrtf(vk * (1.0f / 1536.0f) + 1e-6f);
#pragma unroll
  for (int j = 0; j < 6; j += 2) {
    int jj = j0 + j;
    int d = jj & 127, i = d >> 1, h = jj >> 7;
    float c = tabc[s * 64 + i], sn = tabs[s * 64 + i];
    size_t base = (((size_t)h * 3584 + s) << 7) + d;
    float a = qv[j] * rq * gq[jj], b = qv[j + 1] * rq * gq[jj + 1];
    qb[base] = (bf16)(a * c - b * sn);
    qb[base + 1] = (bf16)(a * sn + b * c);
    float ak = kv[j] * rk * gk[jj], bk2 = kv[j + 1] * rk * gk[jj + 1];
    kb[base] = (bf16)(ak * c - bk2 * sn);
    kb[base + 1] = (bf16)(ak * sn + bk2 * c);
  }
}

// ---------------- V slice -> transposed bf16 vT [12][128][3584] ----------------
__global__ __launch_bounds__(256) void transpose_v(const bf16* __restrict__ QKV,
                                                   bf16* __restrict__ vT) {
  __shared__ bf16 tile[128][72];
  int t = threadIdx.x;
  int h = blockIdx.y;
  int s0 = blockIdx.x * 64;
  int r = t >> 2, c0 = (t & 3) * 32;
  const bf16* src = QKV + (size_t)(s0 + r) * 4608 + 3072 + h * 128 + c0;
#pragma unroll
  for (int q = 0; q < 4; ++q) {
    bf16x8 v = ld8(src + q * 8);
#pragma unroll
    for (int j = 0; j < 8; ++j) tile[c0 + q * 8 + j][r] = v[j];
  }
  __syncthreads();
  int d = t >> 1, sp = (t & 1) * 32;
  bf16* dst = vT + (size_t)(h * 128 + d) * 3584 + s0 + sp;
#pragma unroll
  for (int q = 0; q < 4; ++q) {
    bf16x8 o;
#pragma unroll
    for (int j = 0; j < 8; ++j) o[j] = tile[d][sp + q * 8 + j];
    *(bf16x8*)(dst + q * 8) = o;
  }
}

// ---------------- flash attention: 4 waves x 32 q-rows, KVBLK=64, reg-staged swizzled LDS ----------------
__global__ __launch_bounds__(256, 2) void flash_attn(
    const bf16* __restrict__ qb, const bf16* __restrict__ kb, const bf16* __restrict__ vT,
    const int* __restrict__ sl, bf16* __restrict__ attn) {
  const int L = 3584;
  __shared__ bf16 Ks[64 * 128];   // [kv][d], XOR-swizzled: byte ^= ((row&7)<<4)
  __shared__ bf16 Vs[128 * 64];   // [d][kv], XOR-swizzled
  __shared__ bf16 Ps[4][32 * 72]; // per-wave P, row stride 72
  int t = threadIdx.x, l = t & 63, w = t >> 6;
  int lane15 = l & 15, lhi = l >> 4;
  int h = blockIdx.y;
  int qw = blockIdx.x * 128 + w * 32;
  int seqlen = sl[0];             // int32 on device
  const float scale = 0.08838834764831845f; // 1/sqrt(128)

  bf16x8 aq[2][4];
#pragma unroll
  for (int mi = 0; mi < 2; ++mi)
#pragma unroll
    for (int kc = 0; kc < 4; ++kc)
      aq[mi][kc] = ld8(qb + (((size_t)h * L + qw + mi * 16 + lane15) << 7) + kc * 32 + lhi * 8);

  f32x4 zero = {0.f, 0.f, 0.f, 0.f};
  f32x4 out[2][8];
  float m[2][4], ls[2][4];
#pragma unroll
  for (int mi = 0; mi < 2; ++mi) {
#pragma unroll
    for (int df = 0; df < 8; ++df) out[mi][df] = zero;
#pragma unroll
    for (int r = 0; r < 4; ++r) { m[mi][r] = -1e30f; ls[mi][r] = 0.f; }
  }

  int nt = (seqlen + 63) >> 6;
  if (nt > 56) nt = 56;
  for (int tile = 0; tile < nt; ++tile) {
    int kv0 = tile * 64;
    // reg-stage K[64][128] and Vt[128][64]; write swizzled, read swizzled (both explicit)
#pragma unroll
    for (int p = 0; p < 4; ++p) {
      int rk = p * 16 + (t >> 4);
      int ckb = (t & 15) * 16;  // byte col in 256B row
      bf16x8 kvv = ld8(kb + (((size_t)h * L + kv0 + rk) << 7) + (ckb >> 1));
      *(bf16x8*)((char*)Ks + rk * 256 + (ckb ^ ((rk & 7) << 4))) = kvv;
      int rv = p * 32 + (t >> 3);
      int cvb = (t & 7) * 16;   // byte col in 128B row
      bf16x8 vvv = ld8(vT + (size_t)(h * 128 + rv) * L + kv0 + (cvb >> 1));
      *(bf16x8*)((char*)Vs + rv * 128 + (cvb ^ ((rv & 7) << 4))) = vvv;
    }
    __syncthreads();

    // S = Q K^T
    f32x4 sc[2][4];
#pragma unroll
    for (int mi = 0; mi < 2; ++mi)
#pragma unroll
      for (int nf = 0; nf < 4; ++nf) sc[mi][nf] = zero;
#pragma unroll
    for (int nf = 0; nf < 4; ++nf)
#pragma unroll
      for (int kc = 0; kc < 4; ++kc) {
        int rk = nf * 16 + lane15;
        int cbs = (kc * 64 + lhi * 16) ^ ((rk & 7) << 4);
        bf16x8 bk_ = ld8((const bf16*)((const char*)Ks + rk * 256 + cbs));
        sc[0][nf] = __builtin_amdgcn_mfma_f32_16x16x32_bf16(aq[0][kc], bk_, sc[0][nf], 0, 0, 0);
        sc[1][nf] = __builtin_amdgcn_mfma_f32_16x16x32_bf16(aq[1][kc], bk_, sc[1][nf], 0, 0, 0);
      }

    // online softmax
#pragma unroll
    for (int mi = 0; mi < 2; ++mi) {
      float mt[4] = {-1e30f, -1e30f, -1e30f, -1e30f};
#pragma unroll
      for (int nf = 0; nf < 4; ++nf) {
        int col = kv0 + nf * 16 + lane15;
        bool valid = col < seqlen;
#pragma unroll
        for (int r = 0; r < 4; ++r) {
          float s = sc[mi][nf][r] * scale;
          s = valid ? s : -1e30f;
          sc[mi][nf][r] = s;
          mt[r] = fmaxf(mt[r], s);
        }
      }
#pragma unroll
      for (int r = 0; r < 4; ++r) {
        float v = mt[r];
        v = fmaxf(v, __shfl_xor(v, 1));
        v = fmaxf(v, __shfl_xor(v, 2));
        v = fmaxf(v, __shfl_xor(v, 4));
        v = fmaxf(v, __shfl_xor(v, 8));
        float nm = fmaxf(m[mi][r], v);
        float f = __expf(m[mi][r] - nm);
        m[mi][r] = nm;
        ls[mi][r] *= f;
#pragma unroll
        for (int df = 0; df < 8; ++df) out[mi][df][r] *= f;
      }
      float ps[4] = {0.f, 0.f, 0.f, 0.f};
#pragma unroll
      for (int nf = 0; nf < 4; ++nf)
#pragma unroll
        for (int r = 0; r < 4; ++r) {
          float p = __expf(sc[mi][nf][r] - m[mi][r]);
          ps[r] += p;
          Ps[w][(mi * 16 + lhi * 4 + r) * 72 + nf * 16 + lane15] = (bf16)p;
        }
#pragma unroll
      for (int r = 0; r < 4; ++r) {
        float v = ps[r];
        v += __shfl_xor(v, 1);
        v += __shfl_xor(v, 2);
        v += __shfl_xor(v, 4);
        v += __shfl_xor(v, 8);
        ls[mi][r] += v;
      }
    }
    __syncthreads();  // fence: P stores visible before PV fragment loads

    // O += P V
    bf16x8 ap[2][2];
#pragma unroll
    for (int mi = 0; mi < 2; ++mi)
#pragma unroll
      for (int kc = 0; kc < 2; ++kc)
        ap[mi][kc] = ld8(&Ps[w][(mi * 16 + lane15) * 72 + kc * 32 + lhi * 8]);
#pragma unroll
    for (int df = 0; df < 8; ++df)
#pragma unroll
      for (int kc = 0; kc < 2; ++kc) {
        int rd = df * 16 + lane15;
        int cbs = (kc * 64 + lhi * 16) ^ ((rd & 7) << 4);
        bf16x8 bv_ = ld8((const bf16*)((const char*)Vs + rd * 128 + cbs));
        out[0][df] = __builtin_amdgcn_mfma_f32_16x16x32_bf16(ap[0][kc], bv_, out[0][df], 0, 0, 0);
        out[1][df] = __builtin_amdgcn_mfma_f32_16x16x32_bf16(ap[1][kc], bv_, out[1][df], 0, 0, 0);
      }
    __syncthreads();
  }

#pragma unroll
  for (int mi = 0; mi < 2; ++mi)
#pragma unroll
    for (int r = 0; r < 4; ++r) {
      float inv = 1.0f / ls[mi][r];
      int row = qw + mi * 16 + lhi * 4 + r;
#pragma unroll
      for (int df = 0; df < 8; ++df)
        attn[(size_t)row * 1536 + h * 128 + df * 16 + lane15] = (bf16)(out[mi][df][r] * inv);
    }
}

// ---------------- launcher ----------------
extern "C" void kernel_launch(void* const* d_in, const int* in_sizes, int n_in,
                              void* d_out, int out_size, void* d_ws, size_t ws_size,
                              hipStream_t stream) {
  const float* x = (const float*)d_in[0];
  const int* seq_lens = (const int*)d_in[1];     // harness: integer inputs are int32
  const int* grid_sizes = (const int*)d_in[2];   // harness: integer inputs are int32
  const float* freqs = (const float*)d_in[3];
  const float* Wq = (const float*)d_in[4];
  const float* bq = (const float*)d_in[5];
  const float* Wk = (const float*)d_in[6];
  const float* bk = (const float*)d_in[7];
  const float* Wv = (const float*)d_in[8];
  const float* bv = (const float*)d_in[9];
  const float* Wo = (const float*)d_in[10];
  const float* bo = (const float*)d_in[11];
  const float* gq = (const float*)d_in[12];
  const float* gk = (const float*)d_in[13];

  char* ws = (char*)d_ws;
  bf16* x_bf = (bf16*)ws;   ws += 11010048;   // 3584*1536 bf16 (reused as attn after QKV GEMM)
  bf16* wqkvt = (bf16*)ws;  ws += 14155776;   // 4608*1536 bf16
  bf16* wot = (bf16*)ws;    ws += 4718592;    // 1536*1536 bf16
  float* bqkv = (float*)ws; ws += 18432;      // 4608 f32
  bf16* QKV = (bf16*)ws;    ws += 33030144;   // 3584*4608 bf16
  bf16* qb = (bf16*)ws;     ws += 11010048;   // [12][3584][128]
  bf16* kb = (bf16*)ws;     ws += 11010048;
  bf16* vT = (bf16*)ws;     ws += 11010048;   // [12][128][3584]
  float* tabc = (float*)ws; ws += 917504;     // [3584][64]
  float* tabs = (float*)ws; ws += 917504;
  bf16* attn = x_bf;        // alias: x_bf dead after QKV GEMM (stream-ordered)

  cast_f32_bf16<<<2688, 256, 0, stream>>>(x, x_bf, 688128);
  transpose_w<<<dim3(24, 24), 256, 0, stream>>>(Wq, wqkvt);
  transpose_w<<<dim3(24, 24), 256, 0, stream>>>(Wk, wqkvt + 1536 * 1536);
  transpose_w<<<dim3(24, 24), 256, 0, stream>>>(Wv, wqkvt + 2 * 1536 * 1536);
  transpose_w<<<dim3(24, 24), 256, 0, stream>>>(Wo, wot);
  concat_bias<<<18, 256, 0, stream>>>(bq, bk, bv, bqkv);
  rope_tab<<<896, 256, 0, stream>>>(freqs, grid_sizes, tabc, tabs);
  gemm_bt<bf16><<<dim3(28, 36), 256, 0, stream>>>(x_bf, wqkvt, bqkv, QKV, 3584, 4608, 1536);
  postproc<<<3584, 256, 0, stream>>>(QKV, gq, gk, tabc, tabs, qb, kb);
  transpose_v<<<dim3(56, 12), 256, 0, stream>>>(QKV, vT);
  flash_attn<<<dim3(28, 12), 256, 0, stream>>>(qb, kb, vT, seq_lens, attn);
  gemm_bt<float><<<dim3(28, 12), 256, 0, stream>>>(attn, wot, bo, (float*)d_out, 3584, 1536, 1536);
}